// Round 10
// baseline (47.941 us; speedup 1.0000x reference)
//
#include <hip/hip_runtime.h>

// Probabilistic Conway forward prop.
// in:  (32, 1024, 1024) float32; out = pmf3 + pmf2 * p_self over 8 Moore
// neighbors (torus), Poisson-binomial pmf truncated at k=3.
//
// Round 10: packed-FP32 (VOP3P v_pk_fma_f32) arithmetic. Output rows paired
// at STRIDE 4: Q[i] = (P[i], P[i+4]). Row-pair k uses a=Q[k], b=Q[k+1],
// cc=Q[k+2] -- all packed operands are whole reused registers (no per-column
// cross-row shuffles), and dd/center alignment is preserved. Halves the
// factorized-pmf VALU stream (~75% of VALU work). Memory structure unchanged
// from round 9: f32x4 loads + fast path, shfl halos + 1 gather, NT stores,
// XCD swizzle, RPT=8.

#define H 1024
#define W 1024
#define RPT 8
#define NROWS (RPT + 2)

typedef float f32x4 __attribute__((ext_vector_type(4)));
typedef float f32x2 __attribute__((ext_vector_type(2)));

__global__ __launch_bounds__(256) void prob_conway_kernel(
    const float* __restrict__ in, float* __restrict__ out) {
    const int nblk = 32 * (H / RPT);       // 4096
    const int cpx  = nblk / 8;             // 512 blocks per XCD chunk
    const int bid  = blockIdx.x;
    const int s    = (bid & 7) * cpx + (bid >> 3);   // bijective swizzle

    const int plane = s >> 7;              // 128 row-groups per plane
    const int rg    = s & 127;
    const int r0    = rg * RPT;
    const int lane  = threadIdx.x & 63;
    const int c0    = threadIdx.x * 4;     // 256 threads cover 1024 cols

    const float* __restrict__ img = in + (size_t)plane * (H * W);
    float* __restrict__ o         = out + (size_t)plane * (H * W);

    // ---- one gather load fetches all 20 wave-edge halo values ----
    const int wbase = (threadIdx.x >> 6) << 8;         // wave base col
    const int clw   = (wbase + W - 1) & (W - 1);
    const int crw   = (wbase + 256) & (W - 1);
    int gi = lane >> 1;
    gi = (gi < NROWS) ? gi : 0;                        // lanes >=20 duplicate
    const int grow = (r0 + gi - 1 + H) & (H - 1);
    const int gcol = (lane & 1) ? crw : clw;
    const float gv = img[(size_t)grow * W + gcol];

    // ---- vector loads: 10 rows x float4 ----
    float P[NROWS][6];
    if (rg != 0 && rg != 127) {
        const float* rp = img + (size_t)(r0 - 1) * W + c0;
#pragma unroll
        for (int i = 0; i < NROWS; ++i) {
            const f32x4 v = *reinterpret_cast<const f32x4*>(rp);
            P[i][1] = v.x; P[i][2] = v.y; P[i][3] = v.z; P[i][4] = v.w;
            rp += W;
        }
    } else {
#pragma unroll
        for (int i = 0; i < NROWS; ++i) {
            const int r = (r0 + i - 1 + H) & (H - 1);
            const f32x4 v =
                *reinterpret_cast<const f32x4*>(img + (size_t)r * W + c0);
            P[i][1] = v.x; P[i][2] = v.y; P[i][3] = v.z; P[i][4] = v.w;
        }
    }

    // ---- distribute halos: interior via shfl, wave edges via gather ----
#pragma unroll
    for (int i = 0; i < NROWS; ++i) {
        const float lv = __shfl_up(P[i][4], 1);        // lane-1's v.w
        const float rv = __shfl_down(P[i][1], 1);      // lane+1's v.x
        const float e  = __shfl(gv, 2 * i + ((lane == 63) ? 1 : 0));
        P[i][0] = (lane == 0)  ? e : lv;
        P[i][5] = (lane == 63) ? e : rv;
    }

    // ---- pack rows at stride 4: Q[i] = (P[i], P[i+4]) ----
    f32x2 Q[6][6];
#pragma unroll
    for (int i = 0; i < 6; ++i)
#pragma unroll
        for (int c = 0; c < 6; ++c)
            Q[i][c] = f32x2{P[i][c], P[i + 4][c]};

    // ---- factorized pmf, packed over row-pairs (k, k+4) ----
#pragma unroll
    for (int k = 0; k < 4; ++k) {
        f32x2 v3[6][4];   // packed V3 per column
        f32x2 dd[4][3];   // packed pair-poly per center column
#pragma unroll
        for (int jc = 0; jc < 6; ++jc) {
            const f32x2 a  = Q[k][jc];          // top rows (k, k+4)
            const f32x2 b  = Q[k + 1][jc];      // mid rows
            const f32x2 cc = Q[k + 2][jc];      // bot rows
            const f32x2 qa = 1.0f - a, qb = 1.0f - b, qc = 1.0f - cc;
            const f32x2 d0 = qa * qc;
            const f32x2 d1 = qa * cc + a * qc;
            const f32x2 d2 = a * cc;
            v3[jc][0] = d0 * qb;
            v3[jc][1] = d1 * qb + d0 * b;
            v3[jc][2] = d2 * qb + d1 * b;
            v3[jc][3] = d2 * b;
            if (jc >= 1 && jc <= 4) {
                dd[jc - 1][0] = d0; dd[jc - 1][1] = d1; dd[jc - 1][2] = d2;
            }
        }
        f32x2 res[4];
#pragma unroll
        for (int x = 0; x < 4; ++x) {
            const f32x2* L = v3[x];
            const f32x2* R = v3[x + 2];
            const f32x2* D = dd[x];
            const f32x2 w0 = L[0] * R[0];
            const f32x2 w1 = L[1] * R[0] + L[0] * R[1];
            const f32x2 w2 = L[2] * R[0] + L[1] * R[1] + L[0] * R[2];
            const f32x2 w3 = L[3] * R[0] + L[2] * R[1] + L[1] * R[2] + L[0] * R[3];
            const f32x2 pmf2 = w2 * D[0] + w1 * D[1] + w0 * D[2];
            const f32x2 pmf3 = w3 * D[0] + w2 * D[1] + w1 * D[2];
            res[x] = pmf3 + pmf2 * Q[k + 1][x + 1];
        }
        // transpose components back to per-row quads, NT-store both rows
        const f32x4 lo = {res[0].x, res[1].x, res[2].x, res[3].x};
        const f32x4 hi = {res[0].y, res[1].y, res[2].y, res[3].y};
        __builtin_nontemporal_store(
            lo, reinterpret_cast<f32x4*>(o + (size_t)(r0 + k) * W + c0));
        __builtin_nontemporal_store(
            hi, reinterpret_cast<f32x4*>(o + (size_t)(r0 + k + 4) * W + c0));
    }
}

extern "C" void kernel_launch(void* const* d_in, const int* in_sizes, int n_in,
                              void* d_out, int out_size, void* d_ws, size_t ws_size,
                              hipStream_t stream) {
    const float* in = (const float*)d_in[0];
    float* out = (float*)d_out;
    dim3 grid(32 * (H / RPT));   // 4096 blocks
    dim3 block(256);
    prob_conway_kernel<<<grid, block, 0, stream>>>(in, out);
}

// Round 11
// 43.959 us; speedup vs baseline: 1.0906x; 1.0906x over previous
//
#include <hip/hip_runtime.h>

// Probabilistic Conway forward prop.
// in:  (32, 1024, 1024) float32; out = pmf3 + pmf2 * p_self over 8 Moore
// neighbors (torus), Poisson-binomial pmf truncated at k=3.
//
// Round 11: occupancy experiment. RPT 8 -> 4 doubles the grid (4096 -> 8192
// blocks) so twice the waves are available to hide HBM latency (round 10
// showed VALU is off the critical path; occupancy ~33% and effective BW only
// ~70% of the copy ceiling). Packed f32x2 core retained with stride-2 row
// pairs Q[i] = (P[i], P[i+2]) -- same zero-shuffle packing property, lower
// VGPR than round 10. Extra vertical read redundancy (1.25x -> 1.5x logical)
// is served by L2/L3. NT stores, shfl halos, XCD swizzle, fast-path rows.

#define H 1024
#define W 1024
#define RPT 4
#define NROWS (RPT + 2)

typedef float f32x4 __attribute__((ext_vector_type(4)));
typedef float f32x2 __attribute__((ext_vector_type(2)));

__global__ __launch_bounds__(256) void prob_conway_kernel(
    const float* __restrict__ in, float* __restrict__ out) {
    const int nblk = 32 * (H / RPT);       // 8192
    const int cpx  = nblk / 8;             // 1024 blocks per XCD chunk
    const int bid  = blockIdx.x;
    const int s    = (bid & 7) * cpx + (bid >> 3);   // bijective swizzle

    const int plane = s >> 8;              // 256 row-groups per plane
    const int rg    = s & 255;
    const int r0    = rg * RPT;
    const int lane  = threadIdx.x & 63;
    const int c0    = threadIdx.x * 4;     // 256 threads cover 1024 cols

    const float* __restrict__ img = in + (size_t)plane * (H * W);
    float* __restrict__ o         = out + (size_t)plane * (H * W);

    // ---- one gather load fetches all 12 wave-edge halo values ----
    const int wbase = (threadIdx.x >> 6) << 8;         // wave base col
    const int clw   = (wbase + W - 1) & (W - 1);
    const int crw   = (wbase + 256) & (W - 1);
    int gi = lane >> 1;
    gi = (gi < NROWS) ? gi : 0;                        // lanes >=12 duplicate
    const int grow = (r0 + gi - 1 + H) & (H - 1);
    const int gcol = (lane & 1) ? crw : clw;
    const float gv = img[(size_t)grow * W + gcol];

    // ---- vector loads: 6 rows x float4 ----
    float P[NROWS][6];
    if (rg != 0 && rg != 255) {
        // Fast path: rows r0-1 .. r0+4 are contiguous, no vertical wrap.
        const float* rp = img + (size_t)(r0 - 1) * W + c0;
#pragma unroll
        for (int i = 0; i < NROWS; ++i) {
            const f32x4 v = *reinterpret_cast<const f32x4*>(rp);
            P[i][1] = v.x; P[i][2] = v.y; P[i][3] = v.z; P[i][4] = v.w;
            rp += W;
        }
    } else {
#pragma unroll
        for (int i = 0; i < NROWS; ++i) {
            const int r = (r0 + i - 1 + H) & (H - 1);
            const f32x4 v =
                *reinterpret_cast<const f32x4*>(img + (size_t)r * W + c0);
            P[i][1] = v.x; P[i][2] = v.y; P[i][3] = v.z; P[i][4] = v.w;
        }
    }

    // ---- distribute halos: interior via shfl, wave edges via gather ----
#pragma unroll
    for (int i = 0; i < NROWS; ++i) {
        const float lv = __shfl_up(P[i][4], 1);        // lane-1's v.w
        const float rv = __shfl_down(P[i][1], 1);      // lane+1's v.x
        const float e  = __shfl(gv, 2 * i + ((lane == 63) ? 1 : 0));
        P[i][0] = (lane == 0)  ? e : lv;
        P[i][5] = (lane == 63) ? e : rv;
    }

    // ---- pack rows at stride 2: Q[i] = (P[i], P[i+2]) ----
    f32x2 Q[4][6];
#pragma unroll
    for (int i = 0; i < 4; ++i)
#pragma unroll
        for (int c = 0; c < 6; ++c)
            Q[i][c] = f32x2{P[i][c], P[i + 2][c]};

    // ---- factorized pmf, packed over row-pairs (k, k+2) ----
#pragma unroll
    for (int k = 0; k < 2; ++k) {
        f32x2 v3[6][4];   // packed V3 per column
        f32x2 dd[4][3];   // packed pair-poly per center column
#pragma unroll
        for (int jc = 0; jc < 6; ++jc) {
            const f32x2 a  = Q[k][jc];          // top rows (k, k+2)
            const f32x2 b  = Q[k + 1][jc];      // mid rows
            const f32x2 cc = Q[k + 2][jc];      // bot rows
            const f32x2 qa = 1.0f - a, qb = 1.0f - b, qc = 1.0f - cc;
            const f32x2 d0 = qa * qc;
            const f32x2 d1 = qa * cc + a * qc;
            const f32x2 d2 = a * cc;
            v3[jc][0] = d0 * qb;
            v3[jc][1] = d1 * qb + d0 * b;
            v3[jc][2] = d2 * qb + d1 * b;
            v3[jc][3] = d2 * b;
            if (jc >= 1 && jc <= 4) {
                dd[jc - 1][0] = d0; dd[jc - 1][1] = d1; dd[jc - 1][2] = d2;
            }
        }
        f32x2 res[4];
#pragma unroll
        for (int x = 0; x < 4; ++x) {
            const f32x2* L = v3[x];
            const f32x2* R = v3[x + 2];
            const f32x2* D = dd[x];
            const f32x2 w0 = L[0] * R[0];
            const f32x2 w1 = L[1] * R[0] + L[0] * R[1];
            const f32x2 w2 = L[2] * R[0] + L[1] * R[1] + L[0] * R[2];
            const f32x2 w3 = L[3] * R[0] + L[2] * R[1] + L[1] * R[2] + L[0] * R[3];
            const f32x2 pmf2 = w2 * D[0] + w1 * D[1] + w0 * D[2];
            const f32x2 pmf3 = w3 * D[0] + w2 * D[1] + w1 * D[2];
            res[x] = pmf3 + pmf2 * Q[k + 1][x + 1];
        }
        // transpose components back to per-row quads, NT-store both rows
        const f32x4 lo = {res[0].x, res[1].x, res[2].x, res[3].x};
        const f32x4 hi = {res[0].y, res[1].y, res[2].y, res[3].y};
        __builtin_nontemporal_store(
            lo, reinterpret_cast<f32x4*>(o + (size_t)(r0 + k) * W + c0));
        __builtin_nontemporal_store(
            hi, reinterpret_cast<f32x4*>(o + (size_t)(r0 + k + 2) * W + c0));
    }
}

extern "C" void kernel_launch(void* const* d_in, const int* in_sizes, int n_in,
                              void* d_out, int out_size, void* d_ws, size_t ws_size,
                              hipStream_t stream) {
    const float* in = (const float*)d_in[0];
    float* out = (float*)d_out;
    dim3 grid(32 * (H / RPT));   // 8192 blocks
    dim3 block(256);
    prob_conway_kernel<<<grid, block, 0, stream>>>(in, out);
}

// Round 12
// 43.779 us; speedup vs baseline: 1.0951x; 1.0041x over previous
//
#include <hip/hip_runtime.h>

// Probabilistic Conway forward prop.
// in:  (32, 1024, 1024) float32; out = pmf3 + pmf2 * p_self over 8 Moore
// neighbors (torus), Poisson-binomial pmf truncated at k=3.
//
// Round 12: intra-wave software pipeline. Rounds 9-11 were lockstep: each
// wave issued all loads, stalled, then computed while issuing nothing ->
// bursty HBM demand, memory pipe idle during compute bursts (44 us wall vs
// 31 us traffic floor; fillBuffer on same profile hits 7 TB/s). Now each
// block covers 8 rows as TWO 4-row halves: all 11 loads issued upfront,
// phase A (rows 0..5) shuffles/computes/stores while phase B's 4 row-loads
// are still in flight (compiler emits counted vmcnt), then phase B. Packed
// f32x2 core per half (stride-2 row pairs), NT stores, shfl halos + 1
// gather, XCD swizzle, fast-path addressing.

#define H 1024
#define W 1024
#define RPB 8            // output rows per block (two halves of 4)
#define NR (RPB + 2)     // rows loaded: r0-1 .. r0+8

typedef float f32x4 __attribute__((ext_vector_type(4)));
typedef float f32x2 __attribute__((ext_vector_type(2)));

__global__ __launch_bounds__(256) void prob_conway_kernel(
    const float* __restrict__ in, float* __restrict__ out) {
    const int nblk = 32 * (H / RPB);       // 4096
    const int cpx  = nblk / 8;             // 512 blocks per XCD chunk
    const int bid  = blockIdx.x;
    const int s    = (bid & 7) * cpx + (bid >> 3);   // bijective swizzle

    const int plane = s >> 7;              // 128 row-groups per plane
    const int rg    = s & 127;
    const int r0    = rg * RPB;
    const int lane  = threadIdx.x & 63;
    const int c0    = threadIdx.x * 4;     // 256 threads cover 1024 cols

    const float* __restrict__ img = in + (size_t)plane * (H * W);
    float* __restrict__ o         = out + (size_t)plane * (H * W);

    // ---- gather load: 20 lanes fetch all wave-edge halos for 10 rows ----
    const int wbase = (threadIdx.x >> 6) << 8;         // wave base col
    const int clw   = (wbase + W - 1) & (W - 1);
    const int crw   = (wbase + 256) & (W - 1);
    int gi = lane >> 1;
    gi = (gi < NR) ? gi : 0;                           // lanes >=20 duplicate
    const int grow = (r0 + gi - 1 + H) & (H - 1);
    const int gcol = (lane & 1) ? crw : clw;
    const float gv = img[(size_t)grow * W + gcol];

    // ---- vector loads: 10 rows x float4, all issued upfront ----
    float P[NR][6];
    if (rg != 0 && rg != 127) {
        const float* rp = img + (size_t)(r0 - 1) * W + c0;
#pragma unroll
        for (int i = 0; i < NR; ++i) {
            const f32x4 v = *reinterpret_cast<const f32x4*>(rp);
            P[i][1] = v.x; P[i][2] = v.y; P[i][3] = v.z; P[i][4] = v.w;
            rp += W;
        }
    } else {
#pragma unroll
        for (int i = 0; i < NR; ++i) {
            const int r = (r0 + i - 1 + H) & (H - 1);
            const f32x4 v =
                *reinterpret_cast<const f32x4*>(img + (size_t)r * W + c0);
            P[i][1] = v.x; P[i][2] = v.y; P[i][3] = v.z; P[i][4] = v.w;
        }
    }

    // halo distribute for one row (interior via shfl, wave edge via gather)
#define HALO(i)                                                         \
    {                                                                   \
        const float lv = __shfl_up(P[i][4], 1);                         \
        const float rv = __shfl_down(P[i][1], 1);                       \
        const float e  = __shfl(gv, 2 * (i) + ((lane == 63) ? 1 : 0));  \
        P[i][0] = (lane == 0)  ? e : lv;                                \
        P[i][5] = (lane == 63) ? e : rv;                                \
    }

    // packed factorized pmf for one half; Q rows are stride-2 pairs.
    // outputs: k=0 -> rows (base, base+2); k=1 -> rows (base+1, base+3)
#define COMPUTE_HALF(Q, base)                                           \
    _Pragma("unroll")                                                   \
    for (int k = 0; k < 2; ++k) {                                       \
        f32x2 v3[6][4];                                                 \
        f32x2 dd[4][3];                                                 \
        _Pragma("unroll")                                               \
        for (int jc = 0; jc < 6; ++jc) {                                \
            const f32x2 a  = Q[k][jc];                                  \
            const f32x2 b  = Q[k + 1][jc];                              \
            const f32x2 cc = Q[k + 2][jc];                              \
            const f32x2 qa = 1.0f - a, qb = 1.0f - b, qc = 1.0f - cc;   \
            const f32x2 d0 = qa * qc;                                   \
            const f32x2 d1 = qa * cc + a * qc;                          \
            const f32x2 d2 = a * cc;                                    \
            v3[jc][0] = d0 * qb;                                        \
            v3[jc][1] = d1 * qb + d0 * b;                               \
            v3[jc][2] = d2 * qb + d1 * b;                               \
            v3[jc][3] = d2 * b;                                         \
            if (jc >= 1 && jc <= 4) {                                   \
                dd[jc - 1][0] = d0; dd[jc - 1][1] = d1;                 \
                dd[jc - 1][2] = d2;                                     \
            }                                                           \
        }                                                               \
        f32x2 res[4];                                                   \
        _Pragma("unroll")                                               \
        for (int x = 0; x < 4; ++x) {                                   \
            const f32x2* L = v3[x];                                     \
            const f32x2* R = v3[x + 2];                                 \
            const f32x2* D = dd[x];                                     \
            const f32x2 w0 = L[0] * R[0];                               \
            const f32x2 w1 = L[1] * R[0] + L[0] * R[1];                 \
            const f32x2 w2 = L[2] * R[0] + L[1] * R[1] + L[0] * R[2];   \
            const f32x2 w3 = L[3] * R[0] + L[2] * R[1] + L[1] * R[2]    \
                           + L[0] * R[3];                               \
            const f32x2 pmf2 = w2 * D[0] + w1 * D[1] + w0 * D[2];       \
            const f32x2 pmf3 = w3 * D[0] + w2 * D[1] + w1 * D[2];       \
            res[x] = pmf3 + pmf2 * Q[k + 1][x + 1];                     \
        }                                                               \
        const f32x4 lo = {res[0].x, res[1].x, res[2].x, res[3].x};      \
        const f32x4 hi = {res[0].y, res[1].y, res[2].y, res[3].y};      \
        __builtin_nontemporal_store(lo,                                 \
            reinterpret_cast<f32x4*>(o + (size_t)((base) + k) * W + c0)); \
        __builtin_nontemporal_store(hi,                                 \
            reinterpret_cast<f32x4*>(o + (size_t)((base) + k + 2) * W + c0)); \
    }

    // ---- phase A: rows 0..5 (output rows r0 .. r0+3) ----
    // Only waits on the first 6 row-loads + gather; rows 6..9 stay in flight.
    HALO(0) HALO(1) HALO(2) HALO(3) HALO(4) HALO(5)
    {
        f32x2 QA[4][6];
#pragma unroll
        for (int i = 0; i < 4; ++i)
#pragma unroll
            for (int c = 0; c < 6; ++c)
                QA[i][c] = f32x2{P[i][c], P[i + 2][c]};
        COMPUTE_HALF(QA, r0)
    }

    // ---- phase B: rows 6..9 (output rows r0+4 .. r0+7) ----
    HALO(6) HALO(7) HALO(8) HALO(9)
    {
        f32x2 QB[4][6];
#pragma unroll
        for (int i = 0; i < 4; ++i)
#pragma unroll
            for (int c = 0; c < 6; ++c)
                QB[i][c] = f32x2{P[i + 4][c], P[i + 6][c]};
        COMPUTE_HALF(QB, r0 + 4)
    }

#undef HALO
#undef COMPUTE_HALF
}

extern "C" void kernel_launch(void* const* d_in, const int* in_sizes, int n_in,
                              void* d_out, int out_size, void* d_ws, size_t ws_size,
                              hipStream_t stream) {
    const float* in = (const float*)d_in[0];
    float* out = (float*)d_out;
    dim3 grid(32 * (H / RPB));   // 4096 blocks
    dim3 block(256);
    prob_conway_kernel<<<grid, block, 0, stream>>>(in, out);
}